// Round 12
// baseline (336.557 us; speedup 1.0000x reference)
//
#include <hip/hip_runtime.h>
#include <hip/hip_bf16.h>
#include <math.h>

typedef unsigned short u16;
typedef __bf16 bf16x8 __attribute__((ext_vector_type(8)));
typedef float f32x4 __attribute__((ext_vector_type(4)));

#define NB 32
#define LSEQ 1024
#define DIN 512
#define EDIM 1024
#define SDIM 128
#define NTOK (NB * LSEQ)       // 32768
#define NUV 2176               // 2E + S
#define CHUNK 16               // batches per qk/pv chunk

#define AS1 __attribute__((address_space(1)))
#define AS3 __attribute__((address_space(3)))

__device__ __forceinline__ u16 f2bf(float f) {
  unsigned u = __builtin_bit_cast(unsigned, f);
  u += 0x7fffu + ((u >> 16) & 1u);
  return (u16)(u >> 16);
}
__device__ __forceinline__ float bf2f(u16 h) {
  unsigned u = ((unsigned)h) << 16;
  return __builtin_bit_cast(float, u);
}
__device__ __forceinline__ float fast_silu(float x) {
  float t = __builtin_amdgcn_exp2f(-1.44269504088896f * x);
  return x * __builtin_amdgcn_rcpf(1.0f + t);
}

// ---------------- small prep kernels ----------------

__global__ __launch_bounds__(256) void k_f32_to_bf16(const float* __restrict__ in,
                                                     u16* __restrict__ out, int n4) {
  int i = blockIdx.x * 256 + threadIdx.x;
  if (i < n4) {
    float4 f = ((const float4*)in)[i];
    ushort4 o;
    o.x = f2bf(f.x); o.y = f2bf(f.y); o.z = f2bf(f.z); o.w = f2bf(f.w);
    ((ushort4*)out)[i] = o;
  }
}

// fused rms-norm + half-shift (reads x once; verified R5)
__global__ __launch_bounds__(256) void k_normshift(const float* __restrict__ x,
                                                   const float* __restrict__ g,
                                                   u16* __restrict__ xn2) {
  int t = blockIdx.x;
  int l = t & (LSEQ - 1);
  float2 v = ((const float2*)(x + (size_t)t * DIN))[threadIdx.x];
  float ss = v.x * v.x + v.y * v.y;
  for (int o = 32; o > 0; o >>= 1) ss += __shfl_down(ss, o, 64);
  __shared__ float p[4];
  if ((threadIdx.x & 63) == 0) p[threadIdx.x >> 6] = ss;
  __syncthreads();
  float s = p[0] + p[1] + p[2] + p[3];
  float norm = sqrtf(s * (1.0f / (float)DIN));
  float inv = g[0] / fmaxf(norm, 1e-5f);
  int d = threadIdx.x * 2;
  ushort2 ob; ob.x = f2bf(v.x * inv); ob.y = f2bf(v.y * inv);
  if (d >= 256) {
    *(ushort2*)(xn2 + (size_t)t * DIN + d) = ob;
  } else {
    if (l < LSEQ - 1) *(ushort2*)(xn2 + (size_t)(t + 1) * DIN + d) = ob;
    if (l == 0) { ushort2 z = {0, 0}; *(ushort2*)(xn2 + (size_t)t * DIN + d) = z; }
  }
}

// RoPE tables in double precision (match numpy)
__global__ __launch_bounds__(256) void k_rope_table(float* __restrict__ sin_t,
                                                    float* __restrict__ cos_t) {
  int idx = blockIdx.x * 256 + threadIdx.x;   // 1024*64
  int l = idx >> 6, j = idx & 63;
  double freq = pow(10000.0, (double)j / 64.0);
  float arg = (float)l * (float)freq;
  double a = (double)arg;
  sin_t[idx] = (float)sin(a);
  cos_t[idx] = (float)cos(a);
}

// base -> q,k with gamma/beta affine + RoPE
__global__ __launch_bounds__(256) void k_qkbuild(const u16* __restrict__ base,
                                                 const float* __restrict__ gamma,
                                                 const float* __restrict__ beta,
                                                 const float* __restrict__ sin_t,
                                                 const float* __restrict__ cos_t,
                                                 u16* __restrict__ q, u16* __restrict__ k) {
  int idx = blockIdx.x * 256 + threadIdx.x;   // NTOK*64
  int t = idx >> 6, j = idx & 63;
  int l = t & (LSEQ - 1);
  float b1 = bf2f(base[(size_t)t * SDIM + j]);
  float b2 = bf2f(base[(size_t)t * SDIM + j + 64]);
  float s = sin_t[l * 64 + j], c = cos_t[l * 64 + j];
  {
    float y1 = b1 * gamma[j] + beta[j];
    float y2 = b2 * gamma[64 + j] + beta[64 + j];
    q[(size_t)t * SDIM + j]      = f2bf(y1 * c - y2 * s);
    q[(size_t)t * SDIM + j + 64] = f2bf(y2 * c + y1 * s);
  }
  {
    float y1 = b1 * gamma[128 + j] + beta[128 + j];
    float y2 = b2 * gamma[192 + j] + beta[192 + j];
    k[(size_t)t * SDIM + j]      = f2bf(y1 * c - y2 * s);
    k[(size_t)t * SDIM + j + 64] = f2bf(y2 * c + y1 * s);
  }
}

// ============ 256x256 8-wave dual-barrier 8-phase core (m201 discipline) ============
// 512 thr = 8 waves (2M x 4N). BK=64, LDS 128KB (2 dbuf x (A 32K + B 32K)), 1 blk/CU.
// Per K-tile, 4 phases: {RD(this phase) + stage(retired region); s_barrier;
// lgkmcnt(0)+sched_barrier; setprio+16 MFMA; s_barrier}. Counted vmcnt(7) once
// per K-tile (phase 3), vmcnt(0) only in epilogue tiles.
// Stage plan for tile t (reading CBUF): ph0: Aq3(t+1)->OBUF; ph1: Aq0(t+2)+B01(t+2)
// ->CBUF; ph2: Aq1+B23; ph3: Aq2. Each region's readers retired one phase earlier.

#define GROW_A(s) (wr * 128 + (s) * 32 + wc * 8)
#define GROW_B(s) (wid * 32 + (s) * 8)

#define STG_A(s, Asrc, dA)                                                         \
  __builtin_amdgcn_global_load_lds(                                               \
      (AS1 unsigned int*)((Asrc) + (size_t)(GROW_A(s) + srow) * lda + scol),       \
      (AS3 unsigned int*)((dA) + GROW_A(s) * 64), 16, 0, 0)
#define STG_B(s, Bsrc, dB)                                                         \
  __builtin_amdgcn_global_load_lds(                                               \
      (AS1 unsigned int*)((Bsrc) + (size_t)(GROW_B(s) + srow) * ldb + scol),       \
      (AS3 unsigned int*)((dB) + GROW_B(s) * 64), 16, 0, 0)

#define RD_A(dst, cbuf, q)                                                         \
  do {                                                                             \
    _Pragma("unroll") for (int r_ = 0; r_ < 2; ++r_)                               \
    _Pragma("unroll") for (int h_ = 0; h_ < 2; ++h_)                               \
      dst[r_][h_] = *(const bf16x8*)((cbuf) + (wr * 128 + (q) * 32 + r_ * 16 + fr) * 64 + \
                                     (((h_ * 4 + kg) ^ fr7) * 8));                 \
  } while (0)

#define RD_B(cbuf)                                                                 \
  do {                                                                             \
    _Pragma("unroll") for (int n_ = 0; n_ < 4; ++n_)                               \
    _Pragma("unroll") for (int h_ = 0; h_ < 2; ++h_)                               \
      breg[n_][h_] = *(const bf16x8*)((cbuf) + (wc * 64 + n_ * 16 + fr) * 64 +     \
                                      (((h_ * 4 + kg) ^ fr7) * 8));                \
  } while (0)

#define MFMA16(s, areg)                                                            \
  do {                                                                             \
    __builtin_amdgcn_s_setprio(1);                                                 \
    _Pragma("unroll") for (int r_ = 0; r_ < 2; ++r_)                               \
    _Pragma("unroll") for (int n_ = 0; n_ < 4; ++n_)                               \
    _Pragma("unroll") for (int h_ = 0; h_ < 2; ++h_)                               \
      acc[(s) * 2 + r_][n_] = __builtin_amdgcn_mfma_f32_16x16x32_bf16(             \
          areg[r_][h_], breg[n_][h_], acc[(s) * 2 + r_][n_], 0, 0, 0);             \
    __builtin_amdgcn_s_setprio(0);                                                 \
  } while (0)

#define BAR_FENCE()                                                                \
  do { __builtin_amdgcn_s_barrier(); asm volatile("" ::: "memory"); } while (0)

// barrier; wait own ds_reads; fence scheduler (rule #18); MFMA; barrier
#define PH_BAR_MFMA(q)                                                             \
  do {                                                                             \
    BAR_FENCE();                                                                   \
    asm volatile("s_waitcnt lgkmcnt(0)" ::: "memory");                             \
    __builtin_amdgcn_sched_barrier(0);                                             \
    MFMA16(q, aq);                                                                 \
    BAR_FENCE();                                                                   \
  } while (0)

#define TILE8(CA, CB, OA, T)                                                       \
  do {                                                                             \
    const u16* At1_ = A + (size_t)((T) + 1) * 64;                                  \
    const u16* At2_ = A + (size_t)((T) + 2) * 64;                                  \
    const u16* Bt2_ = B + (size_t)((T) + 2) * 64;                                  \
    const bool s1_ = ((T) + 1) < nt;                                               \
    const bool s2_ = ((T) + 2) < nt;                                               \
    /* phase 0 */                                                                  \
    RD_B(CB); RD_A(aq, CA, 0);                                                     \
    if (s1_) STG_A(3, At1_, OA);                                                   \
    asm volatile("s_waitcnt lgkmcnt(8)" ::: "memory");                             \
    PH_BAR_MFMA(0);                                                                \
    /* phase 1 */                                                                  \
    RD_A(aq, CA, 1);                                                               \
    if (s2_) { STG_A(0, At2_, CA); STG_B(0, Bt2_, CB); STG_B(1, Bt2_, CB); }       \
    PH_BAR_MFMA(1);                                                                \
    /* phase 2 */                                                                  \
    RD_A(aq, CA, 2);                                                               \
    if (s2_) { STG_A(1, At2_, CA); STG_B(2, Bt2_, CB); STG_B(3, Bt2_, CB); }       \
    PH_BAR_MFMA(2);                                                                \
    /* phase 3 + K-tile boundary: counted vmcnt */                                 \
    RD_A(aq, CA, 3);                                                               \
    if (s2_) { STG_A(2, At2_, CA); asm volatile("s_waitcnt vmcnt(7)" ::: "memory"); } \
    else     { asm volatile("s_waitcnt vmcnt(0)" ::: "memory"); }                  \
    PH_BAR_MFMA(3);                                                                \
  } while (0)

__device__ __forceinline__ void gemm256p_core(const u16* __restrict__ A, int lda,
                                              const u16* __restrict__ B, int ldb,
                                              int K, u16* smem, f32x4 (&acc)[8][4]) {
  const int tid = threadIdx.x;
  const int lane = tid & 63, wid = tid >> 6;
  const int wr = wid >> 2, wc = wid & 3;
  const int fr = lane & 15, kg = lane >> 4, fr7 = fr & 7;
  const int srow = lane >> 3;
  const int scol = ((lane & 7) ^ srow) * 8;
  u16* const A0 = smem;
  u16* const B0 = smem + 16384;
  u16* const A1 = smem + 32768;
  u16* const B1 = smem + 49152;
  const int nt = K >> 6;   // even for all callers (2, 8, 16)

  // prologue: tile0 full (8 loads), tile1 minus Aq3 (7 loads)
  STG_A(0, A, A0); STG_A(1, A, A0); STG_A(2, A, A0); STG_A(3, A, A0);
  STG_B(0, B, B0); STG_B(1, B, B0); STG_B(2, B, B0); STG_B(3, B, B0);
  STG_A(0, A + 64, A1); STG_A(1, A + 64, A1); STG_A(2, A + 64, A1);
  STG_B(0, B + 64, B1); STG_B(1, B + 64, B1); STG_B(2, B + 64, B1); STG_B(3, B + 64, B1);
  asm volatile("s_waitcnt vmcnt(7)" ::: "memory");   // tile0's 8 landed
  __builtin_amdgcn_sched_barrier(0);
  BAR_FENCE();

  bf16x8 breg[4][2], aq[2][2];

  for (int tt = 0; tt < nt; tt += 2) {
    TILE8(A0, B0, A1, tt);
    TILE8(A1, B1, A0, tt + 1);
  }
}

// GEMM1: uv = silu(xn2 @ uv_w^T). Grid 1152 = 8 XCDs x 16 M-tiles x 9 N-tiles.
__global__ __launch_bounds__(512, 2) void k_gemm_uv(const u16* __restrict__ xn2,
                                                    const u16* __restrict__ wbf,
                                                    u16* __restrict__ u, u16* __restrict__ vt,
                                                    u16* __restrict__ base) {
  __shared__ __align__(16) u16 smem[65536];
  f32x4 acc[8][4] = {};
  int bid = blockIdx.x;
  int xcd = bid & 7;
  int off = bid >> 3;                 // 0..143
  int m0 = (xcd * 16 + off / 9) * 256;
  int n0 = (off % 9) * 256;
  gemm256p_core(xn2 + (size_t)m0 * DIN, DIN, wbf + (size_t)n0 * DIN, DIN, DIN, smem, acc);
  int lane = threadIdx.x & 63, wid = threadIdx.x >> 6;
  int wr = wid >> 2, wc = wid & 3;
  int cb = n0 + wc * 64 + (lane & 15);
  int rb = m0 + wr * 128 + (lane >> 4) * 4;
  if (n0 < EDIM) {                       // u columns
#pragma unroll
    for (int mm = 0; mm < 8; ++mm)
#pragma unroll
      for (int n = 0; n < 4; ++n) {
        int c = cb + n * 16;
#pragma unroll
        for (int j = 0; j < 4; ++j) {
          int r = rb + mm * 16 + j;
          u[(size_t)r * EDIM + c] = f2bf(fast_silu(acc[mm][n][j]));
        }
      }
  } else if (n0 < 2 * EDIM) {            // v columns -> transposed store
    int b = m0 >> 10;
    u16* vtb = vt + (size_t)b * (EDIM * LSEQ);
#pragma unroll
    for (int mm = 0; mm < 8; ++mm) {
      int l0 = (rb + mm * 16) & (LSEQ - 1);
#pragma unroll
      for (int n = 0; n < 4; ++n) {
        int e = cb + n * 16 - EDIM;
        ushort4 o;
        o.x = f2bf(fast_silu(acc[mm][n][0]));
        o.y = f2bf(fast_silu(acc[mm][n][1]));
        o.z = f2bf(fast_silu(acc[mm][n][2]));
        o.w = f2bf(fast_silu(acc[mm][n][3]));
        *(ushort4*)(vtb + (size_t)e * LSEQ + l0) = o;
      }
    }
  } else if (wc < 2) {                   // base columns (valid half-tile)
#pragma unroll
    for (int mm = 0; mm < 8; ++mm)
#pragma unroll
      for (int n = 0; n < 4; ++n) {
        int c = cb + n * 16 - 2 * EDIM;
#pragma unroll
        for (int j = 0; j < 4; ++j) {
          int r = rb + mm * 16 + j;
          base[(size_t)r * SDIM + c] = f2bf(fast_silu(acc[mm][n][j]));
        }
      }
  }
}

// GEMM2: scores = relu((q k^T + w)/sqrt(S))^2.  nt=2.
// Grid 256 = 8 XCDs x 2 batches x 16 tiles (16 batches per launch).
__global__ __launch_bounds__(512, 2) void k_gemm_qk(const u16* __restrict__ q,
                                                    const u16* __restrict__ k,
                                                    const float* __restrict__ w,
                                                    u16* __restrict__ scores) {
  __shared__ __align__(16) u16 smem[65536];
  f32x4 acc[8][4] = {};
  int bid = blockIdx.x;
  int xcd = bid & 7;
  int off = bid >> 3;                    // 0..31
  int b = xcd * 2 + (off >> 4);          // chunk-local batch
  int t = off & 15;
  int m0 = (t >> 2) * 256, n0 = (t & 3) * 256;
  gemm256p_core(q + (size_t)(b * LSEQ + m0) * SDIM, SDIM,
                k + (size_t)(b * LSEQ + n0) * SDIM, SDIM,
                SDIM, smem, acc);
  int lane = threadIdx.x & 63, wid = threadIdx.x >> 6;
  int wr = wid >> 2, wc = wid & 3;
  int cb = n0 + wc * 64 + (lane & 15);
  int rb = m0 + wr * 128 + (lane >> 4) * 4;
  const float inv_sqrt_s = 0.08838834764831845f;
  u16* sc_b = scores + (size_t)b * LSEQ * LSEQ;
#pragma unroll
  for (int mm = 0; mm < 8; ++mm)
#pragma unroll
    for (int n = 0; n < 4; ++n) {
      int c = cb + n * 16;
#pragma unroll
      for (int j = 0; j < 4; ++j) {
        int r = rb + mm * 16 + j;
        float val = (acc[mm][n][j] + w[c - r + (LSEQ - 1)]) * inv_sqrt_s;
        val = fmaxf(val, 0.0f);
        sc_b[(size_t)r * LSEQ + c] = f2bf(val * val);
      }
    }
}

// GEMM3: u_io <- u_io .* (scores @ v).
// Grid 256 = 8 XCDs x 2 batches x 16 tiles (16 batches per launch).
__global__ __launch_bounds__(512, 2) void k_gemm_pv(const u16* __restrict__ scores,
                                                    const u16* __restrict__ vt,
                                                    u16* u_io) {
  __shared__ __align__(16) u16 smem[65536];
  f32x4 acc[8][4] = {};
  int bid = blockIdx.x;
  int xcd = bid & 7;
  int off = bid >> 3;                    // 0..31
  int b = xcd * 2 + (off >> 4);          // chunk-local batch
  int t = off & 15;
  int m0 = (t >> 2) * 256, n0 = (t & 3) * 256;
  gemm256p_core(scores + (size_t)b * LSEQ * LSEQ + (size_t)m0 * LSEQ, LSEQ,
                vt + (size_t)b * LSEQ * EDIM + (size_t)n0 * LSEQ, LSEQ,
                LSEQ, smem, acc);
  int lane = threadIdx.x & 63, wid = threadIdx.x >> 6;
  int wr = wid >> 2, wc = wid & 3;
  int cb = n0 + wc * 64 + (lane & 15);
  int rb = m0 + wr * 128 + (lane >> 4) * 4;
#pragma unroll
  for (int mm = 0; mm < 8; ++mm)
#pragma unroll
    for (int n = 0; n < 4; ++n) {
      int c = cb + n * 16;
#pragma unroll
      for (int j = 0; j < 4; ++j) {
        int r = rb + mm * 16 + j;
        size_t idx = (size_t)(b * LSEQ + r) * EDIM + c;
        u_io[idx] = f2bf(acc[mm][n][j] * bf2f(u_io[idx]));
      }
    }
}

// GEMM4: out = x*res_scale + (attn @ o_w^T)*layer_scale.
// Grid 256 = 8 XCDs x 16 M-tiles x 2 N-tiles.
__global__ __launch_bounds__(512, 2) void k_gemm_out(const u16* __restrict__ attn,
                                                     const u16* __restrict__ owbf,
                                                     const float* __restrict__ x,
                                                     const float* __restrict__ res_scale,
                                                     const float* __restrict__ layer_scale,
                                                     float* __restrict__ out) {
  __shared__ __align__(16) u16 smem[65536];
  f32x4 acc[8][4] = {};
  int bid = blockIdx.x;
  int xcd = bid & 7;
  int off = bid >> 3;                 // 0..31
  int m0 = (xcd * 16 + (off >> 1)) * 256;
  int n0 = (off & 1) * 256;
  gemm256p_core(attn + (size_t)m0 * EDIM, EDIM, owbf + (size_t)n0 * EDIM, EDIM,
                EDIM, smem, acc);
  int lane = threadIdx.x & 63, wid = threadIdx.x >> 6;
  int wr = wid >> 2, wc = wid & 3;
  int cb = n0 + wc * 64 + (lane & 15);
  int rb = m0 + wr * 128 + (lane >> 4) * 4;
#pragma unroll
  for (int mm = 0; mm < 8; ++mm)
#pragma unroll
    for (int n = 0; n < 4; ++n) {
      int c = cb + n * 16;
#pragma unroll
      for (int j = 0; j < 4; ++j) {
        int r = rb + mm * 16 + j;
        out[(size_t)r * DIN + c] =
            x[(size_t)r * DIN + c] * res_scale[c] + acc[mm][n][j] * layer_scale[c];
      }
    }
}

// ---------------- launch ----------------

extern "C" void kernel_launch(void* const* d_in, const int* in_sizes, int n_in,
                              void* d_out, int out_size, void* d_ws, size_t ws_size,
                              hipStream_t stream) {
  const float* x          = (const float*)d_in[0];
  const float* uv_w       = (const float*)d_in[1];
  const float* o_w        = (const float*)d_in[2];
  const float* gamma      = (const float*)d_in[3];
  const float* beta       = (const float*)d_in[4];
  const float* w          = (const float*)d_in[5];
  const float* g          = (const float*)d_in[6];
  const float* res_scale  = (const float*)d_in[7];
  const float* layer_scale= (const float*)d_in[8];
  float* out = (float*)d_out;

  char* ws = (char*)d_ws;
  // workspace layout (bytes), peak ~189 MB (< proven-good 197):
  u16* xn2    = (u16*)(ws + 0);            // 32 MB, dead after gemm_uv
  u16* q      = (u16*)(ws + 0);            // 8 MB (aliases dead xn2)
  u16* k      = (u16*)(ws + 8388608);      // 8 MB (aliases dead xn2)
  u16* scores = (u16*)(ws + 16777216);     // 32 MB (aliases dead xn2-upper + dead base)
  u16* base   = (u16*)(ws + 33554432);     // 8 MB, live gemm_uv -> qkbuild
  u16* u_io   = (u16*)(ws + 50331648);     // 64 MB: u, gated in place -> attn
  u16* vt     = (u16*)(ws + 117440512);    // 64 MB: v^T per batch
  u16* uvw_bf = (u16*)(ws + 184549376);    // 2.125 MB (+0.125 MB pad-read slack)
  u16* ow_bf  = (u16*)(ws + 186908672);    // 1 MB
  float* sin_t = (float*)(ws + 187957248); // 256 KB
  float* cos_t = (float*)(ws + 188219392); // 256 KB

  // prep
  k_f32_to_bf16<<<dim3((NUV * DIN / 4 + 255) / 256), 256, 0, stream>>>(uv_w, uvw_bf, NUV * DIN / 4);
  k_f32_to_bf16<<<dim3((DIN * EDIM / 4 + 255) / 256), 256, 0, stream>>>(o_w, ow_bf, DIN * EDIM / 4);
  k_rope_table<<<dim3(LSEQ * 64 / 256), 256, 0, stream>>>(sin_t, cos_t);
  k_normshift<<<dim3(NTOK), 256, 0, stream>>>(x, g, xn2);

  // uv projection + silu
  k_gemm_uv<<<dim3(1152), 512, 0, stream>>>(xn2, uvw_bf, u_io, vt, base);

  // q,k build (writes into dead xn2 region)
  k_qkbuild<<<dim3(NTOK * 64 / 256), 256, 0, stream>>>(base, gamma, beta, sin_t, cos_t, q, k);

  // scores + pv, chunked by 16 batches (scores = 32 MB, reused)
  for (int ch = 0; ch < NB / CHUNK; ++ch) {
    size_t tok0 = (size_t)ch * CHUNK * LSEQ;
    k_gemm_qk<<<dim3(256), 512, 0, stream>>>(q + tok0 * SDIM, k + tok0 * SDIM, w, scores);
    k_gemm_pv<<<dim3(256), 512, 0, stream>>>(scores, vt + tok0 * EDIM, u_io + tok0 * EDIM);
  }

  // final projection + residual
  k_gemm_out<<<dim3(256), 512, 0, stream>>>(u_io, ow_bf, x, res_scale, layer_scale, out);
}

// Round 13
// 311.947 us; speedup vs baseline: 1.0789x; 1.0789x over previous
//
#include <hip/hip_runtime.h>
#include <hip/hip_bf16.h>
#include <math.h>

typedef unsigned short u16;
typedef __bf16 bf16x8 __attribute__((ext_vector_type(8)));
typedef float f32x4 __attribute__((ext_vector_type(4)));

#define NB 32
#define LSEQ 1024
#define DIN 512
#define EDIM 1024
#define SDIM 128
#define NTOK (NB * LSEQ)       // 32768
#define NUV 2176               // 2E + S
#define CHUNK 16               // batches per qk/pv chunk

#define AS1 __attribute__((address_space(1)))
#define AS3 __attribute__((address_space(3)))

__device__ __forceinline__ u16 f2bf(float f) {
  unsigned u = __builtin_bit_cast(unsigned, f);
  u += 0x7fffu + ((u >> 16) & 1u);
  return (u16)(u >> 16);
}
__device__ __forceinline__ float bf2f(u16 h) {
  unsigned u = ((unsigned)h) << 16;
  return __builtin_bit_cast(float, u);
}
__device__ __forceinline__ float fast_silu(float x) {
  float t = __builtin_amdgcn_exp2f(-1.44269504088896f * x);
  return x * __builtin_amdgcn_rcpf(1.0f + t);
}

// ---------------- small prep kernels ----------------

__global__ __launch_bounds__(256) void k_f32_to_bf16(const float* __restrict__ in,
                                                     u16* __restrict__ out, int n4) {
  int i = blockIdx.x * 256 + threadIdx.x;
  if (i < n4) {
    float4 f = ((const float4*)in)[i];
    ushort4 o;
    o.x = f2bf(f.x); o.y = f2bf(f.y); o.z = f2bf(f.z); o.w = f2bf(f.w);
    ((ushort4*)out)[i] = o;
  }
}

// fused rms-norm + half-shift (reads x once; verified R5)
__global__ __launch_bounds__(256) void k_normshift(const float* __restrict__ x,
                                                   const float* __restrict__ g,
                                                   u16* __restrict__ xn2) {
  int t = blockIdx.x;
  int l = t & (LSEQ - 1);
  float2 v = ((const float2*)(x + (size_t)t * DIN))[threadIdx.x];
  float ss = v.x * v.x + v.y * v.y;
  for (int o = 32; o > 0; o >>= 1) ss += __shfl_down(ss, o, 64);
  __shared__ float p[4];
  if ((threadIdx.x & 63) == 0) p[threadIdx.x >> 6] = ss;
  __syncthreads();
  float s = p[0] + p[1] + p[2] + p[3];
  float norm = sqrtf(s * (1.0f / (float)DIN));
  float inv = g[0] / fmaxf(norm, 1e-5f);
  int d = threadIdx.x * 2;
  ushort2 ob; ob.x = f2bf(v.x * inv); ob.y = f2bf(v.y * inv);
  if (d >= 256) {
    *(ushort2*)(xn2 + (size_t)t * DIN + d) = ob;
  } else {
    if (l < LSEQ - 1) *(ushort2*)(xn2 + (size_t)(t + 1) * DIN + d) = ob;
    if (l == 0) { ushort2 z = {0, 0}; *(ushort2*)(xn2 + (size_t)t * DIN + d) = z; }
  }
}

// RoPE tables in double precision (match numpy)
__global__ __launch_bounds__(256) void k_rope_table(float* __restrict__ sin_t,
                                                    float* __restrict__ cos_t) {
  int idx = blockIdx.x * 256 + threadIdx.x;   // 1024*64
  int l = idx >> 6, j = idx & 63;
  double freq = pow(10000.0, (double)j / 64.0);
  float arg = (float)l * (float)freq;
  double a = (double)arg;
  sin_t[idx] = (float)sin(a);
  cos_t[idx] = (float)cos(a);
}

// ============ 256x256 8-wave pipelined core (R11-verified: static buffers) ============

#define GROW_A(s) (wr * 128 + (s) * 32 + wc * 8)
#define GROW_B(s) (wid * 32 + (s) * 8)

#define STG_PAIR(s, At2, Bt2, dA, dB)                                              \
  do {                                                                             \
    __builtin_amdgcn_global_load_lds(                                              \
        (AS1 unsigned int*)((At2) + (size_t)(GROW_A(s) + srow) * lda + scol),      \
        (AS3 unsigned int*)((dA) + GROW_A(s) * 64), 16, 0, 0);                     \
    __builtin_amdgcn_global_load_lds(                                              \
        (AS1 unsigned int*)((Bt2) + (size_t)(GROW_B(s) + srow) * ldb + scol),      \
        (AS3 unsigned int*)((dB) + GROW_B(s) * 64), 16, 0, 0);                     \
  } while (0)

#define RD_A(dst, cbuf, q)                                                         \
  do {                                                                             \
    _Pragma("unroll") for (int r_ = 0; r_ < 2; ++r_)                               \
    _Pragma("unroll") for (int h_ = 0; h_ < 2; ++h_)                               \
      dst[r_][h_] = *(const bf16x8*)((cbuf) + (wr * 128 + (q) * 32 + r_ * 16 + fr) * 64 + \
                                     (((h_ * 4 + kg) ^ fr7) * 8));                 \
  } while (0)

#define RD_B(cbuf)                                                                 \
  do {                                                                             \
    _Pragma("unroll") for (int n_ = 0; n_ < 4; ++n_)                               \
    _Pragma("unroll") for (int h_ = 0; h_ < 2; ++h_)                               \
      breg[n_][h_] = *(const bf16x8*)((cbuf) + (wc * 64 + n_ * 16 + fr) * 64 +     \
                                      (((h_ * 4 + kg) ^ fr7) * 8));                \
  } while (0)

#define MFMA16(s, areg)                                                            \
  do {                                                                             \
    __builtin_amdgcn_s_setprio(1);                                                 \
    _Pragma("unroll") for (int r_ = 0; r_ < 2; ++r_)                               \
    _Pragma("unroll") for (int n_ = 0; n_ < 4; ++n_)                               \
    _Pragma("unroll") for (int h_ = 0; h_ < 2; ++h_)                               \
      acc[(s) * 2 + r_][n_] = __builtin_amdgcn_mfma_f32_16x16x32_bf16(             \
          areg[r_][h_], breg[n_][h_], acc[(s) * 2 + r_][n_], 0, 0, 0);             \
    __builtin_amdgcn_s_setprio(0);                                                 \
  } while (0)

#define BAR_FENCE()                                                                \
  do { __builtin_amdgcn_s_barrier(); asm volatile("" ::: "memory"); } while (0)

#define TILE_STEP(CA, CB, OA, OB, T)                                               \
  do {                                                                             \
    const bool st_ = ((T) + 2) < nt;                                               \
    const bool more_ = ((T) + 1) < nt;                                             \
    const u16* At2_ = A + (size_t)((T) + 2) * 64;                                  \
    const u16* Bt2_ = B + (size_t)((T) + 2) * 64;                                  \
    MFMA16(0, ac);                                                                 \
    RD_A(an, CA, 1);                                                               \
    BAR_FENCE();                                                                   \
    if (st_) STG_PAIR(0, At2_, Bt2_, CA, CB);                                      \
    MFMA16(1, an);                                                                 \
    RD_A(ac, CA, 2);                                                               \
    BAR_FENCE();                                                                   \
    if (st_) STG_PAIR(1, At2_, Bt2_, CA, CB);                                      \
    MFMA16(2, ac);                                                                 \
    RD_A(an, CA, 3);                                                               \
    BAR_FENCE();                                                                   \
    if (st_) STG_PAIR(2, At2_, Bt2_, CA, CB);                                      \
    MFMA16(3, an);                                                                 \
    if (st_) asm volatile("s_waitcnt vmcnt(6)" ::: "memory");                      \
    else     asm volatile("s_waitcnt vmcnt(0)" ::: "memory");                      \
    BAR_FENCE();                                                                   \
    if (st_) STG_PAIR(3, At2_, Bt2_, CA, CB);                                      \
    if (more_) { RD_B(OB); RD_A(ac, OA, 0); }                                      \
  } while (0)

__device__ __forceinline__ void gemm256p_core(const u16* __restrict__ A, int lda,
                                              const u16* __restrict__ B, int ldb,
                                              int K, u16* smem, f32x4 (&acc)[8][4]) {
  const int tid = threadIdx.x;
  const int lane = tid & 63, wid = tid >> 6;
  const int wr = wid >> 2, wc = wid & 3;
  const int fr = lane & 15, kg = lane >> 4, fr7 = fr & 7;
  const int srow = lane >> 3;
  const int scol = ((lane & 7) ^ srow) * 8;
  u16* const A0 = smem;
  u16* const B0 = smem + 16384;
  u16* const A1 = smem + 32768;
  u16* const B1 = smem + 49152;
  const int nt = K >> 6;   // even for all callers (2, 8, 16)

#pragma unroll
  for (int s = 0; s < 4; ++s) STG_PAIR(s, A, B, A0, B0);
#pragma unroll
  for (int s = 0; s < 4; ++s) STG_PAIR(s, A + 64, B + 64, A1, B1);
  asm volatile("s_waitcnt vmcnt(8)" ::: "memory");
  BAR_FENCE();

  bf16x8 breg[4][2], ac[2][2], an[2][2];
  RD_B(B0);
  RD_A(ac, A0, 0);

  for (int tt = 0; tt < nt; tt += 2) {
    TILE_STEP(A0, B0, A1, B1, tt);
    TILE_STEP(A1, B1, A0, B0, tt + 1);
  }
}

// GEMM1: uv = silu(xn2 @ uv_w^T). Grid 1152 = 8 XCDs x 16 M-tiles x 9 N-tiles.
// N-tiles 0-3 -> u; 4-7 -> v transposed (vt[b][e][l]); tile 8 -> base cols:
// FUSED qk build: base tile staged in LDS, gamma/beta + RoPE applied, q/k
// written directly (replaces the separate k_qkbuild kernel + base buffer).
__global__ __launch_bounds__(512, 2) void k_gemm_uv(const u16* __restrict__ xn2,
                                                    const u16* __restrict__ wbf,
                                                    u16* __restrict__ u, u16* __restrict__ vt,
                                                    const float* __restrict__ gamma,
                                                    const float* __restrict__ beta,
                                                    const float* __restrict__ sin_t,
                                                    const float* __restrict__ cos_t,
                                                    u16* __restrict__ qout,
                                                    u16* __restrict__ kout) {
  __shared__ __align__(16) u16 smem[65536];
  f32x4 acc[8][4] = {};
  int bid = blockIdx.x;
  int xcd = bid & 7;
  int off = bid >> 3;                 // 0..143
  int m0 = (xcd * 16 + off / 9) * 256;
  int n0 = (off % 9) * 256;
  gemm256p_core(xn2 + (size_t)m0 * DIN, DIN, wbf + (size_t)n0 * DIN, DIN, DIN, smem, acc);
  int lane = threadIdx.x & 63, wid = threadIdx.x >> 6;
  int wr = wid >> 2, wc = wid & 3;
  int cb = n0 + wc * 64 + (lane & 15);
  int rb = m0 + wr * 128 + (lane >> 4) * 4;
  if (n0 < EDIM) {                       // u columns
#pragma unroll
    for (int mm = 0; mm < 8; ++mm)
#pragma unroll
      for (int n = 0; n < 4; ++n) {
        int c = cb + n * 16;
#pragma unroll
        for (int j = 0; j < 4; ++j) {
          int r = rb + mm * 16 + j;
          u[(size_t)r * EDIM + c] = f2bf(fast_silu(acc[mm][n][j]));
        }
      }
  } else if (n0 < 2 * EDIM) {            // v columns -> transposed store
    int b = m0 >> 10;
    u16* vtb = vt + (size_t)b * (EDIM * LSEQ);
#pragma unroll
    for (int mm = 0; mm < 8; ++mm) {
      int l0 = (rb + mm * 16) & (LSEQ - 1);
#pragma unroll
      for (int n = 0; n < 4; ++n) {
        int e = cb + n * 16 - EDIM;
        ushort4 o;
        o.x = f2bf(fast_silu(acc[mm][n][0]));
        o.y = f2bf(fast_silu(acc[mm][n][1]));
        o.z = f2bf(fast_silu(acc[mm][n][2]));
        o.w = f2bf(fast_silu(acc[mm][n][3]));
        *(ushort4*)(vtb + (size_t)e * LSEQ + l0) = o;
      }
    }
  } else {                               // base tile -> fused gamma/beta + RoPE -> q,k
    u16* sbase = smem;                   // [256][136] padded (69.7KB <= 128KB)
    if (wc < 2) {
#pragma unroll
      for (int mm = 0; mm < 8; ++mm)
#pragma unroll
        for (int n = 0; n < 4; ++n) {
          int c = wc * 64 + (lane & 15) + n * 16;      // 0..127 local
#pragma unroll
          for (int j = 0; j < 4; ++j) {
            int r = wr * 128 + mm * 16 + (lane >> 4) * 4 + j;  // 0..255 local
            sbase[r * 136 + c] = f2bf(fast_silu(acc[mm][n][j]));
          }
        }
    }
    __syncthreads();
    int tid = threadIdx.x;
    int j = tid & 63;
    float g0 = gamma[j], g1 = gamma[64 + j], g2 = gamma[128 + j], g3 = gamma[192 + j];
    float e0 = beta[j],  e1 = beta[64 + j],  e2 = beta[128 + j],  e3 = beta[192 + j];
#pragma unroll 4
    for (int i = 0; i < 32; ++i) {
      int row = (tid >> 6) + i * 8;      // covers 0..255
      int t = m0 + row;
      int l = t & (LSEQ - 1);
      float b1 = bf2f(sbase[row * 136 + j]);
      float b2 = bf2f(sbase[row * 136 + j + 64]);
      float sn = sin_t[l * 64 + j], cs = cos_t[l * 64 + j];
      float y1 = b1 * g0 + e0, y2 = b2 * g1 + e1;
      qout[(size_t)t * SDIM + j]      = f2bf(y1 * cs - y2 * sn);
      qout[(size_t)t * SDIM + j + 64] = f2bf(y2 * cs + y1 * sn);
      y1 = b1 * g2 + e2; y2 = b2 * g3 + e3;
      kout[(size_t)t * SDIM + j]      = f2bf(y1 * cs - y2 * sn);
      kout[(size_t)t * SDIM + j + 64] = f2bf(y2 * cs + y1 * sn);
    }
  }
}

// GEMM2: scores = relu((q k^T + w)/sqrt(S))^2.  nt=2.
// Grid 256 = 8 XCDs x 2 batches x 16 tiles (16 batches per launch).
__global__ __launch_bounds__(512, 2) void k_gemm_qk(const u16* __restrict__ q,
                                                    const u16* __restrict__ k,
                                                    const float* __restrict__ w,
                                                    u16* __restrict__ scores) {
  __shared__ __align__(16) u16 smem[65536];
  f32x4 acc[8][4] = {};
  int bid = blockIdx.x;
  int xcd = bid & 7;
  int off = bid >> 3;                    // 0..31
  int b = xcd * 2 + (off >> 4);          // chunk-local batch
  int t = off & 15;
  int m0 = (t >> 2) * 256, n0 = (t & 3) * 256;
  gemm256p_core(q + (size_t)(b * LSEQ + m0) * SDIM, SDIM,
                k + (size_t)(b * LSEQ + n0) * SDIM, SDIM,
                SDIM, smem, acc);
  int lane = threadIdx.x & 63, wid = threadIdx.x >> 6;
  int wr = wid >> 2, wc = wid & 3;
  int cb = n0 + wc * 64 + (lane & 15);
  int rb = m0 + wr * 128 + (lane >> 4) * 4;
  const float inv_sqrt_s = 0.08838834764831845f;
  u16* sc_b = scores + (size_t)b * LSEQ * LSEQ;
#pragma unroll
  for (int mm = 0; mm < 8; ++mm)
#pragma unroll
    for (int n = 0; n < 4; ++n) {
      int c = cb + n * 16;
#pragma unroll
      for (int j = 0; j < 4; ++j) {
        int r = rb + mm * 16 + j;
        float val = (acc[mm][n][j] + w[c - r + (LSEQ - 1)]) * inv_sqrt_s;
        val = fmaxf(val, 0.0f);
        sc_b[(size_t)r * LSEQ + c] = f2bf(val * val);
      }
    }
}

// GEMM3: u_io <- u_io .* (scores @ v).
// Grid 256 = 8 XCDs x 2 batches x 16 tiles (16 batches per launch).
__global__ __launch_bounds__(512, 2) void k_gemm_pv(const u16* __restrict__ scores,
                                                    const u16* __restrict__ vt,
                                                    u16* u_io) {
  __shared__ __align__(16) u16 smem[65536];
  f32x4 acc[8][4] = {};
  int bid = blockIdx.x;
  int xcd = bid & 7;
  int off = bid >> 3;                    // 0..31
  int b = xcd * 2 + (off >> 4);          // chunk-local batch
  int t = off & 15;
  int m0 = (t >> 2) * 256, n0 = (t & 3) * 256;
  gemm256p_core(scores + (size_t)b * LSEQ * LSEQ + (size_t)m0 * LSEQ, LSEQ,
                vt + (size_t)b * LSEQ * EDIM + (size_t)n0 * LSEQ, LSEQ,
                LSEQ, smem, acc);
  int lane = threadIdx.x & 63, wid = threadIdx.x >> 6;
  int wr = wid >> 2, wc = wid & 3;
  int cb = n0 + wc * 64 + (lane & 15);
  int rb = m0 + wr * 128 + (lane >> 4) * 4;
#pragma unroll
  for (int mm = 0; mm < 8; ++mm)
#pragma unroll
    for (int n = 0; n < 4; ++n) {
      int c = cb + n * 16;
#pragma unroll
      for (int j = 0; j < 4; ++j) {
        int r = rb + mm * 16 + j;
        size_t idx = (size_t)(b * LSEQ + r) * EDIM + c;
        u_io[idx] = f2bf(acc[mm][n][j] * bf2f(u_io[idx]));
      }
    }
}

// GEMM4: out = x*res_scale + (attn @ o_w^T)*layer_scale.
// Grid 256 = 8 XCDs x 16 M-tiles x 2 N-tiles.
__global__ __launch_bounds__(512, 2) void k_gemm_out(const u16* __restrict__ attn,
                                                     const u16* __restrict__ owbf,
                                                     const float* __restrict__ x,
                                                     const float* __restrict__ res_scale,
                                                     const float* __restrict__ layer_scale,
                                                     float* __restrict__ out) {
  __shared__ __align__(16) u16 smem[65536];
  f32x4 acc[8][4] = {};
  int bid = blockIdx.x;
  int xcd = bid & 7;
  int off = bid >> 3;                 // 0..31
  int m0 = (xcd * 16 + (off >> 1)) * 256;
  int n0 = (off & 1) * 256;
  gemm256p_core(attn + (size_t)m0 * EDIM, EDIM, owbf + (size_t)n0 * EDIM, EDIM,
                EDIM, smem, acc);
  int lane = threadIdx.x & 63, wid = threadIdx.x >> 6;
  int wr = wid >> 2, wc = wid & 3;
  int cb = n0 + wc * 64 + (lane & 15);
  int rb = m0 + wr * 128 + (lane >> 4) * 4;
#pragma unroll
  for (int mm = 0; mm < 8; ++mm)
#pragma unroll
    for (int n = 0; n < 4; ++n) {
      int c = cb + n * 16;
#pragma unroll
      for (int j = 0; j < 4; ++j) {
        int r = rb + mm * 16 + j;
        out[(size_t)r * DIN + c] =
            x[(size_t)r * DIN + c] * res_scale[c] + acc[mm][n][j] * layer_scale[c];
      }
    }
}

// ---------------- launch ----------------

extern "C" void kernel_launch(void* const* d_in, const int* in_sizes, int n_in,
                              void* d_out, int out_size, void* d_ws, size_t ws_size,
                              hipStream_t stream) {
  const float* x          = (const float*)d_in[0];
  const float* uv_w       = (const float*)d_in[1];
  const float* o_w        = (const float*)d_in[2];
  const float* gamma      = (const float*)d_in[3];
  const float* beta       = (const float*)d_in[4];
  const float* w          = (const float*)d_in[5];
  const float* g          = (const float*)d_in[6];
  const float* res_scale  = (const float*)d_in[7];
  const float* layer_scale= (const float*)d_in[8];
  float* out = (float*)d_out;

  char* ws = (char*)d_ws;
  // workspace layout (bytes), peak ~180 MB (< proven-good 197).
  // Alias audit: scores(0-32M) aliases xn2(0-32M), dead after uv.
  // q/k (32-48M) written by uv (reads xn2 0-32M): disjoint. qk reads q/k,
  // writes scores (0-32M): disjoint.
  u16* xn2    = (u16*)(ws + 0);            // 32 MB, dead after gemm_uv
  u16* scores = (u16*)(ws + 0);            // 32 MB (aliases dead xn2)
  u16* q      = (u16*)(ws + 33554432);     // 8 MB
  u16* k      = (u16*)(ws + 41943040);     // 8 MB
  u16* u_io   = (u16*)(ws + 50331648);     // 64 MB: u, gated in place -> attn
  u16* vt     = (u16*)(ws + 117440512);    // 64 MB: v^T per batch
  u16* uvw_bf = (u16*)(ws + 184549376);    // 2.125 MB (+slack for tile-8 pad reads)
  u16* ow_bf  = (u16*)(ws + 187170816);    // 1 MB
  float* sin_t = (float*)(ws + 188219392); // 256 KB
  float* cos_t = (float*)(ws + 188481536); // 256 KB

  // prep
  k_f32_to_bf16<<<dim3((NUV * DIN / 4 + 255) / 256), 256, 0, stream>>>(uv_w, uvw_bf, NUV * DIN / 4);
  k_f32_to_bf16<<<dim3((DIN * EDIM / 4 + 255) / 256), 256, 0, stream>>>(o_w, ow_bf, DIN * EDIM / 4);
  k_rope_table<<<dim3(LSEQ * 64 / 256), 256, 0, stream>>>(sin_t, cos_t);
  k_normshift<<<dim3(NTOK), 256, 0, stream>>>(x, g, xn2);

  // uv projection + silu + fused qk build (v written transposed)
  k_gemm_uv<<<dim3(1152), 512, 0, stream>>>(xn2, uvw_bf, u_io, vt,
                                            gamma, beta, sin_t, cos_t, q, k);

  // scores + pv, chunked by 16 batches (scores = 32 MB, aliases dead xn2)
  for (int ch = 0; ch < NB / CHUNK; ++ch) {
    size_t tok0 = (size_t)ch * CHUNK * LSEQ;
    k_gemm_qk<<<dim3(256), 512, 0, stream>>>(q + tok0 * SDIM, k + tok0 * SDIM, w, scores);
    k_gemm_pv<<<dim3(256), 512, 0, stream>>>(scores, vt + tok0 * EDIM, u_io + tok0 * EDIM);
  }

  // final projection + residual
  k_gemm_out<<<dim3(256), 512, 0, stream>>>(u_io, ow_bf, x, res_scale, layer_scale, out);
}

// Round 14
// 309.640 us; speedup vs baseline: 1.0869x; 1.0075x over previous
//
#include <hip/hip_runtime.h>
#include <hip/hip_bf16.h>
#include <math.h>

typedef unsigned short u16;
typedef __bf16 bf16x8 __attribute__((ext_vector_type(8)));
typedef float f32x16 __attribute__((ext_vector_type(16)));

#define NB 32
#define LSEQ 1024
#define DIN 512
#define EDIM 1024
#define SDIM 128
#define NTOK (NB * LSEQ)       // 32768
#define NUV 2176               // 2E + S
#define CHUNK 16               // batches per qk/pv chunk

#define AS1 __attribute__((address_space(1)))
#define AS3 __attribute__((address_space(3)))

__device__ __forceinline__ u16 f2bf(float f) {
  unsigned u = __builtin_bit_cast(unsigned, f);
  u += 0x7fffu + ((u >> 16) & 1u);
  return (u16)(u >> 16);
}
__device__ __forceinline__ float bf2f(u16 h) {
  unsigned u = ((unsigned)h) << 16;
  return __builtin_bit_cast(float, u);
}
__device__ __forceinline__ float fast_silu(float x) {
  float t = __builtin_amdgcn_exp2f(-1.44269504088896f * x);
  return x * __builtin_amdgcn_rcpf(1.0f + t);
}

// ---------------- small prep kernels ----------------

__global__ __launch_bounds__(256) void k_f32_to_bf16(const float* __restrict__ in,
                                                     u16* __restrict__ out, int n4) {
  int i = blockIdx.x * 256 + threadIdx.x;
  if (i < n4) {
    float4 f = ((const float4*)in)[i];
    ushort4 o;
    o.x = f2bf(f.x); o.y = f2bf(f.y); o.z = f2bf(f.z); o.w = f2bf(f.w);
    ((ushort4*)out)[i] = o;
  }
}

// fused rms-norm + half-shift (reads x once; verified R5)
__global__ __launch_bounds__(256) void k_normshift(const float* __restrict__ x,
                                                   const float* __restrict__ g,
                                                   u16* __restrict__ xn2) {
  int t = blockIdx.x;
  int l = t & (LSEQ - 1);
  float2 v = ((const float2*)(x + (size_t)t * DIN))[threadIdx.x];
  float ss = v.x * v.x + v.y * v.y;
  for (int o = 32; o > 0; o >>= 1) ss += __shfl_down(ss, o, 64);
  __shared__ float p[4];
  if ((threadIdx.x & 63) == 0) p[threadIdx.x >> 6] = ss;
  __syncthreads();
  float s = p[0] + p[1] + p[2] + p[3];
  float norm = sqrtf(s * (1.0f / (float)DIN));
  float inv = g[0] / fmaxf(norm, 1e-5f);
  int d = threadIdx.x * 2;
  ushort2 ob; ob.x = f2bf(v.x * inv); ob.y = f2bf(v.y * inv);
  if (d >= 256) {
    *(ushort2*)(xn2 + (size_t)t * DIN + d) = ob;
  } else {
    if (l < LSEQ - 1) *(ushort2*)(xn2 + (size_t)(t + 1) * DIN + d) = ob;
    if (l == 0) { ushort2 z = {0, 0}; *(ushort2*)(xn2 + (size_t)t * DIN + d) = z; }
  }
}

// RoPE tables in double precision (match numpy)
__global__ __launch_bounds__(256) void k_rope_table(float* __restrict__ sin_t,
                                                    float* __restrict__ cos_t) {
  int idx = blockIdx.x * 256 + threadIdx.x;   // 1024*64
  int l = idx >> 6, j = idx & 63;
  double freq = pow(10000.0, (double)j / 64.0);
  float arg = (float)l * (float)freq;
  double a = (double)arg;
  sin_t[idx] = (float)sin(a);
  cos_t[idx] = (float)cos(a);
}

// ===== 256x256 8-wave pipelined core (R11 schedule; R14: 32x32x16 MFMA) =====
// LDS layout/staging/swizzle/barriers/vmcnt identical to R11 (verified).
// Fragments: A row = lane&31, k-slot = kk*2 + (lane>>5), slot XOR (row&7).
// acc: 4 M-pos x 2 N-pos of f32x16 (C/D: col=lane&31, row=(reg&3)+8*(reg>>2)+4*(lane>>5)).

#define GROW_A(s) (wr * 128 + (s) * 32 + wc * 8)
#define GROW_B(s) (wid * 32 + (s) * 8)

#define STG_PAIR(s, At2, Bt2, dA, dB)                                              \
  do {                                                                             \
    __builtin_amdgcn_global_load_lds(                                              \
        (AS1 unsigned int*)((At2) + (size_t)(GROW_A(s) + srow) * lda + scol),      \
        (AS3 unsigned int*)((dA) + GROW_A(s) * 64), 16, 0, 0);                     \
    __builtin_amdgcn_global_load_lds(                                              \
        (AS1 unsigned int*)((Bt2) + (size_t)(GROW_B(s) + srow) * ldb + scol),      \
        (AS3 unsigned int*)((dB) + GROW_B(s) * 64), 16, 0, 0);                     \
  } while (0)

#define RD_A32(dst, cbuf, q)                                                       \
  do {                                                                             \
    _Pragma("unroll") for (int kk_ = 0; kk_ < 4; ++kk_)                            \
      dst[kk_] = *(const bf16x8*)((cbuf) + (wr * 128 + (q) * 32 + l31) * 64 +      \
                                  (((kk_ * 2 + hi) ^ l7) * 8));                    \
  } while (0)

#define RD_B32(cbuf)                                                               \
  do {                                                                             \
    _Pragma("unroll") for (int np_ = 0; np_ < 2; ++np_)                            \
    _Pragma("unroll") for (int kk_ = 0; kk_ < 4; ++kk_)                            \
      breg[np_][kk_] = *(const bf16x8*)((cbuf) + (wc * 64 + np_ * 32 + l31) * 64 + \
                                        (((kk_ * 2 + hi) ^ l7) * 8));              \
  } while (0)

#define MFMA8(s, areg)                                                             \
  do {                                                                             \
    __builtin_amdgcn_s_setprio(1);                                                 \
    _Pragma("unroll") for (int kk_ = 0; kk_ < 4; ++kk_)                            \
    _Pragma("unroll") for (int np_ = 0; np_ < 2; ++np_)                            \
      acc[s][np_] = __builtin_amdgcn_mfma_f32_32x32x16_bf16(                       \
          areg[kk_], breg[np_][kk_], acc[s][np_], 0, 0, 0);                        \
    __builtin_amdgcn_s_setprio(0);                                                 \
  } while (0)

#define BAR_FENCE()                                                                \
  do { __builtin_amdgcn_s_barrier(); asm volatile("" ::: "memory"); } while (0)

#define TILE_STEP(CA, CB, OA, OB, T)                                               \
  do {                                                                             \
    const bool st_ = ((T) + 2) < nt;                                               \
    const bool more_ = ((T) + 1) < nt;                                             \
    const u16* At2_ = A + (size_t)((T) + 2) * 64;                                  \
    const u16* Bt2_ = B + (size_t)((T) + 2) * 64;                                  \
    MFMA8(0, ac);                                                                  \
    RD_A32(an, CA, 1);                                                             \
    BAR_FENCE();                                                                   \
    if (st_) STG_PAIR(0, At2_, Bt2_, CA, CB);                                      \
    MFMA8(1, an);                                                                  \
    RD_A32(ac, CA, 2);                                                             \
    BAR_FENCE();                                                                   \
    if (st_) STG_PAIR(1, At2_, Bt2_, CA, CB);                                      \
    MFMA8(2, ac);                                                                  \
    RD_A32(an, CA, 3);                                                             \
    BAR_FENCE();                                                                   \
    if (st_) STG_PAIR(2, At2_, Bt2_, CA, CB);                                      \
    MFMA8(3, an);                                                                  \
    if (st_) asm volatile("s_waitcnt vmcnt(6)" ::: "memory");                      \
    else     asm volatile("s_waitcnt vmcnt(0)" ::: "memory");                      \
    BAR_FENCE();                                                                   \
    if (st_) STG_PAIR(3, At2_, Bt2_, CA, CB);                                      \
    if (more_) { RD_B32(OB); RD_A32(ac, OA, 0); }                                  \
  } while (0)

__device__ __forceinline__ void gemm256p_core(const u16* __restrict__ A, int lda,
                                              const u16* __restrict__ B, int ldb,
                                              int K, u16* smem, f32x16 (&acc)[4][2]) {
  const int tid = threadIdx.x;
  const int lane = tid & 63, wid = tid >> 6;
  const int wr = wid >> 2, wc = wid & 3;
  const int l31 = lane & 31, hi = lane >> 5, l7 = lane & 7;
  const int srow = lane >> 3;
  const int scol = ((lane & 7) ^ srow) * 8;
  u16* const A0 = smem;
  u16* const B0 = smem + 16384;
  u16* const A1 = smem + 32768;
  u16* const B1 = smem + 49152;
  const int nt = K >> 6;   // even for all callers (2, 8, 16)

#pragma unroll
  for (int s = 0; s < 4; ++s) STG_PAIR(s, A, B, A0, B0);
#pragma unroll
  for (int s = 0; s < 4; ++s) STG_PAIR(s, A + 64, B + 64, A1, B1);
  asm volatile("s_waitcnt vmcnt(8)" ::: "memory");
  BAR_FENCE();

  bf16x8 breg[2][4], ac[4], an[4];
  RD_B32(B0);
  RD_A32(ac, A0, 0);

  for (int tt = 0; tt < nt; tt += 2) {
    TILE_STEP(A0, B0, A1, B1, tt);
    TILE_STEP(A1, B1, A0, B0, tt + 1);
  }
}

// Epilogue index helper (32x32 C/D layout):
//   r = m0 + wr*128 + q*32 + g*8 + hi*4 + j   (reg = g*4+j)
//   c = n0 + wc*64 + np*32 + l31

// GEMM1: uv = silu(xn2 @ uv_w^T). Grid 1152 = 8 XCDs x 16 M x 9 N.
// N-tiles 0-3 -> u; 4-7 -> vt[b][e][l]; tile 8 -> fused gamma/beta+RoPE -> q,k.
__global__ __launch_bounds__(512, 2) void k_gemm_uv(const u16* __restrict__ xn2,
                                                    const u16* __restrict__ wbf,
                                                    u16* __restrict__ u, u16* __restrict__ vt,
                                                    const float* __restrict__ gamma,
                                                    const float* __restrict__ beta,
                                                    const float* __restrict__ sin_t,
                                                    const float* __restrict__ cos_t,
                                                    u16* __restrict__ qout,
                                                    u16* __restrict__ kout) {
  __shared__ __align__(16) u16 smem[65536];
  f32x16 acc[4][2] = {};
  int bid = blockIdx.x;
  int xcd = bid & 7;
  int off = bid >> 3;                 // 0..143
  int m0 = (xcd * 16 + off / 9) * 256;
  int n0 = (off % 9) * 256;
  gemm256p_core(xn2 + (size_t)m0 * DIN, DIN, wbf + (size_t)n0 * DIN, DIN, DIN, smem, acc);
  int lane = threadIdx.x & 63, wid = threadIdx.x >> 6;
  int wr = wid >> 2, wc = wid & 3;
  int l31 = lane & 31, hi = lane >> 5;
  if (n0 < EDIM) {                       // u columns
#pragma unroll
    for (int q = 0; q < 4; ++q)
#pragma unroll
      for (int np = 0; np < 2; ++np) {
        int c = n0 + wc * 64 + np * 32 + l31;
#pragma unroll
        for (int g = 0; g < 4; ++g)
#pragma unroll
          for (int j = 0; j < 4; ++j) {
            int r = m0 + wr * 128 + q * 32 + g * 8 + hi * 4 + j;
            u[(size_t)r * EDIM + c] = f2bf(fast_silu(acc[q][np][g * 4 + j]));
          }
      }
  } else if (n0 < 2 * EDIM) {            // v columns -> transposed store
    int b = m0 >> 10;
    u16* vtb = vt + (size_t)b * (EDIM * LSEQ);
#pragma unroll
    for (int q = 0; q < 4; ++q)
#pragma unroll
      for (int np = 0; np < 2; ++np) {
        int e = n0 - EDIM + wc * 64 + np * 32 + l31;
#pragma unroll
        for (int g = 0; g < 4; ++g) {
          int l0 = (m0 & (LSEQ - 1)) + wr * 128 + q * 32 + g * 8 + hi * 4;
          ushort4 o;
          o.x = f2bf(fast_silu(acc[q][np][g * 4 + 0]));
          o.y = f2bf(fast_silu(acc[q][np][g * 4 + 1]));
          o.z = f2bf(fast_silu(acc[q][np][g * 4 + 2]));
          o.w = f2bf(fast_silu(acc[q][np][g * 4 + 3]));
          *(ushort4*)(vtb + (size_t)e * LSEQ + l0) = o;
        }
      }
  } else {                               // base tile -> fused gamma/beta + RoPE -> q,k
    u16* sbase = smem;                   // [256][136] padded
    if (wc < 2) {
#pragma unroll
      for (int q = 0; q < 4; ++q)
#pragma unroll
        for (int np = 0; np < 2; ++np) {
          int c = wc * 64 + np * 32 + l31;       // 0..127 local
#pragma unroll
          for (int g = 0; g < 4; ++g)
#pragma unroll
            for (int j = 0; j < 4; ++j) {
              int r = wr * 128 + q * 32 + g * 8 + hi * 4 + j;  // 0..255 local
              sbase[r * 136 + c] = f2bf(fast_silu(acc[q][np][g * 4 + j]));
            }
        }
    }
    __syncthreads();
    int tid = threadIdx.x;
    int j = tid & 63;
    float g0 = gamma[j], g1 = gamma[64 + j], g2 = gamma[128 + j], g3 = gamma[192 + j];
    float e0 = beta[j],  e1 = beta[64 + j],  e2 = beta[128 + j],  e3 = beta[192 + j];
#pragma unroll 4
    for (int i = 0; i < 32; ++i) {
      int row = (tid >> 6) + i * 8;      // covers 0..255
      int t = m0 + row;
      int l = t & (LSEQ - 1);
      float b1 = bf2f(sbase[row * 136 + j]);
      float b2 = bf2f(sbase[row * 136 + j + 64]);
      float sn = sin_t[l * 64 + j], cs = cos_t[l * 64 + j];
      float y1 = b1 * g0 + e0, y2 = b2 * g1 + e1;
      qout[(size_t)t * SDIM + j]      = f2bf(y1 * cs - y2 * sn);
      qout[(size_t)t * SDIM + j + 64] = f2bf(y2 * cs + y1 * sn);
      y1 = b1 * g2 + e2; y2 = b2 * g3 + e3;
      kout[(size_t)t * SDIM + j]      = f2bf(y1 * cs - y2 * sn);
      kout[(size_t)t * SDIM + j + 64] = f2bf(y2 * cs + y1 * sn);
    }
  }
}

// GEMM2: scores = relu((q k^T + w)/sqrt(S))^2.  nt=2.
// Grid 256 = 8 XCDs x 2 batches x 16 tiles (16 batches per launch).
__global__ __launch_bounds__(512, 2) void k_gemm_qk(const u16* __restrict__ q_,
                                                    const u16* __restrict__ k_,
                                                    const float* __restrict__ w,
                                                    u16* __restrict__ scores) {
  __shared__ __align__(16) u16 smem[65536];
  f32x16 acc[4][2] = {};
  int bid = blockIdx.x;
  int xcd = bid & 7;
  int off = bid >> 3;                    // 0..31
  int b = xcd * 2 + (off >> 4);          // chunk-local batch
  int t = off & 15;
  int m0 = (t >> 2) * 256, n0 = (t & 3) * 256;
  gemm256p_core(q_ + (size_t)(b * LSEQ + m0) * SDIM, SDIM,
                k_ + (size_t)(b * LSEQ + n0) * SDIM, SDIM,
                SDIM, smem, acc);
  int lane = threadIdx.x & 63, wid = threadIdx.x >> 6;
  int wr = wid >> 2, wc = wid & 3;
  int l31 = lane & 31, hi = lane >> 5;
  const float inv_sqrt_s = 0.08838834764831845f;
  u16* sc_b = scores + (size_t)b * LSEQ * LSEQ;
#pragma unroll
  for (int q = 0; q < 4; ++q)
#pragma unroll
    for (int np = 0; np < 2; ++np) {
      int c = n0 + wc * 64 + np * 32 + l31;
#pragma unroll
      for (int g = 0; g < 4; ++g)
#pragma unroll
        for (int j = 0; j < 4; ++j) {
          int r = m0 + wr * 128 + q * 32 + g * 8 + hi * 4 + j;
          float val = (acc[q][np][g * 4 + j] + w[c - r + (LSEQ - 1)]) * inv_sqrt_s;
          val = fmaxf(val, 0.0f);
          sc_b[(size_t)r * LSEQ + c] = f2bf(val * val);
        }
    }
}

// GEMM3: u_io <- u_io .* (scores @ v).
// Grid 256 = 8 XCDs x 2 batches x 16 tiles (16 batches per launch).
__global__ __launch_bounds__(512, 2) void k_gemm_pv(const u16* __restrict__ scores,
                                                    const u16* __restrict__ vt,
                                                    u16* u_io) {
  __shared__ __align__(16) u16 smem[65536];
  f32x16 acc[4][2] = {};
  int bid = blockIdx.x;
  int xcd = bid & 7;
  int off = bid >> 3;                    // 0..31
  int b = xcd * 2 + (off >> 4);          // chunk-local batch
  int t = off & 15;
  int m0 = (t >> 2) * 256, n0 = (t & 3) * 256;
  gemm256p_core(scores + (size_t)b * LSEQ * LSEQ + (size_t)m0 * LSEQ, LSEQ,
                vt + (size_t)b * LSEQ * EDIM + (size_t)n0 * LSEQ, LSEQ,
                LSEQ, smem, acc);
  int lane = threadIdx.x & 63, wid = threadIdx.x >> 6;
  int wr = wid >> 2, wc = wid & 3;
  int l31 = lane & 31, hi = lane >> 5;
#pragma unroll
  for (int q = 0; q < 4; ++q)
#pragma unroll
    for (int np = 0; np < 2; ++np) {
      int c = n0 + wc * 64 + np * 32 + l31;
#pragma unroll
      for (int g = 0; g < 4; ++g)
#pragma unroll
        for (int j = 0; j < 4; ++j) {
          int r = m0 + wr * 128 + q * 32 + g * 8 + hi * 4 + j;
          size_t idx = (size_t)(b * LSEQ + r) * EDIM + c;
          u_io[idx] = f2bf(acc[q][np][g * 4 + j] * bf2f(u_io[idx]));
        }
    }
}

// GEMM4: out = x*res_scale + (attn @ o_w^T)*layer_scale.
// Grid 256 = 8 XCDs x 16 M-tiles x 2 N-tiles.
__global__ __launch_bounds__(512, 2) void k_gemm_out(const u16* __restrict__ attn,
                                                     const u16* __restrict__ owbf,
                                                     const float* __restrict__ x,
                                                     const float* __restrict__ res_scale,
                                                     const float* __restrict__ layer_scale,
                                                     float* __restrict__ out) {
  __shared__ __align__(16) u16 smem[65536];
  f32x16 acc[4][2] = {};
  int bid = blockIdx.x;
  int xcd = bid & 7;
  int off = bid >> 3;                 // 0..31
  int m0 = (xcd * 16 + (off >> 1)) * 256;
  int n0 = (off & 1) * 256;
  gemm256p_core(attn + (size_t)m0 * EDIM, EDIM, owbf + (size_t)n0 * EDIM, EDIM,
                EDIM, smem, acc);
  int lane = threadIdx.x & 63, wid = threadIdx.x >> 6;
  int wr = wid >> 2, wc = wid & 3;
  int l31 = lane & 31, hi = lane >> 5;
#pragma unroll
  for (int q = 0; q < 4; ++q)
#pragma unroll
    for (int np = 0; np < 2; ++np) {
      int c = n0 + wc * 64 + np * 32 + l31;
#pragma unroll
      for (int g = 0; g < 4; ++g)
#pragma unroll
        for (int j = 0; j < 4; ++j) {
          int r = m0 + wr * 128 + q * 32 + g * 8 + hi * 4 + j;
          out[(size_t)r * DIN + c] =
              x[(size_t)r * DIN + c] * res_scale[c] + acc[q][np][g * 4 + j] * layer_scale[c];
        }
    }
}

// ---------------- launch ----------------

extern "C" void kernel_launch(void* const* d_in, const int* in_sizes, int n_in,
                              void* d_out, int out_size, void* d_ws, size_t ws_size,
                              hipStream_t stream) {
  const float* x          = (const float*)d_in[0];
  const float* uv_w       = (const float*)d_in[1];
  const float* o_w        = (const float*)d_in[2];
  const float* gamma      = (const float*)d_in[3];
  const float* beta       = (const float*)d_in[4];
  const float* w          = (const float*)d_in[5];
  const float* g          = (const float*)d_in[6];
  const float* res_scale  = (const float*)d_in[7];
  const float* layer_scale= (const float*)d_in[8];
  float* out = (float*)d_out;

  char* ws = (char*)d_ws;
  // workspace layout (bytes), peak ~180 MB (< proven-good 197).
  u16* xn2    = (u16*)(ws + 0);            // 32 MB, dead after gemm_uv
  u16* scores = (u16*)(ws + 0);            // 32 MB (aliases dead xn2)
  u16* q      = (u16*)(ws + 33554432);     // 8 MB
  u16* k      = (u16*)(ws + 41943040);     // 8 MB
  u16* u_io   = (u16*)(ws + 50331648);     // 64 MB: u, gated in place -> attn
  u16* vt     = (u16*)(ws + 117440512);    // 64 MB: v^T per batch
  u16* uvw_bf = (u16*)(ws + 184549376);    // 2.125 MB (+slack for tile-8 pad reads)
  u16* ow_bf  = (u16*)(ws + 187170816);    // 1 MB
  float* sin_t = (float*)(ws + 188219392); // 256 KB
  float* cos_t = (float*)(ws + 188481536); // 256 KB

  // prep
  k_f32_to_bf16<<<dim3((NUV * DIN / 4 + 255) / 256), 256, 0, stream>>>(uv_w, uvw_bf, NUV * DIN / 4);
  k_f32_to_bf16<<<dim3((DIN * EDIM / 4 + 255) / 256), 256, 0, stream>>>(o_w, ow_bf, DIN * EDIM / 4);
  k_rope_table<<<dim3(LSEQ * 64 / 256), 256, 0, stream>>>(sin_t, cos_t);
  k_normshift<<<dim3(NTOK), 256, 0, stream>>>(x, g, xn2);

  // uv projection + silu + fused qk build (v written transposed)
  k_gemm_uv<<<dim3(1152), 512, 0, stream>>>(xn2, uvw_bf, u_io, vt,
                                            gamma, beta, sin_t, cos_t, q, k);

  // scores + pv, chunked by 16 batches (scores = 32 MB, aliases dead xn2)
  for (int ch = 0; ch < NB / CHUNK; ++ch) {
    size_t tok0 = (size_t)ch * CHUNK * LSEQ;
    k_gemm_qk<<<dim3(256), 512, 0, stream>>>(q + tok0 * SDIM, k + tok0 * SDIM, w, scores);
    k_gemm_pv<<<dim3(256), 512, 0, stream>>>(scores, vt + tok0 * EDIM, u_io + tok0 * EDIM);
  }

  // final projection + residual
  k_gemm_out<<<dim3(256), 512, 0, stream>>>(u_io, ow_bf, x, res_scale, layer_scale, out);
}